// Round 10
// baseline (512.687 us; speedup 1.0000x reference)
//
#include <hip/hip_runtime.h>
#include <hip/hip_bf16.h>

#define DIN 128
#define DH 32
#define DOUT 2
#define NPB 128            // nodes per bucket
#define NPB_SHIFT 7
#define NBUK_MAX 1024      // supports n <= 131072 (17-bit src packing)
#define FILL_EDGES 8192    // edges per binning block
#define CHUNK 2048         // agg1 scatter chunk
#define PAD 48             // slot strip per node per chunk (Poisson(16) tail safe)

// ---------------------------------------------------------------------------
// workspace (~20.5 MB, budget ~26.8 MB):
//   dinv float[n]; gcnt/gbase/gcur int[NBUK_MAX]
//   binned uint[E]: (dst&127)<<17 | src, grouped by 128-node bucket
//   mqc bf16[n*32]: dinv-scaled layer-1 messages;  m2q float2[n]
// ---------------------------------------------------------------------------

__device__ inline unsigned short f2bf(float f) {
    unsigned int u = __float_as_uint(f);
    u = (u + 0x7FFFu + ((u >> 16) & 1u)) >> 16;
    return (unsigned short)u;
}
__device__ inline float bf2f(unsigned short b) {
    return __uint_as_float(((unsigned int)b) << 16);
}

__global__ void zero_gcnt_kernel(int* __restrict__ gcnt, int nbuk) {
    int i = blockIdx.x * blockDim.x + threadIdx.x;
    if (i < nbuk) gcnt[i] = 0;
}

// bucket-level histogram, LDS-staged
__global__ void bukhist_kernel(const int* __restrict__ dst, int* __restrict__ gcnt,
                               int e, int nbuk) {
    __shared__ int lcnt[NBUK_MAX];
    int t = threadIdx.x;
    for (int i = t; i < nbuk; i += 256) lcnt[i] = 0;
    __syncthreads();
    int e0 = blockIdx.x * FILL_EDGES;
    int m = min(FILL_EDGES, e - e0);
    for (int i = t; i < m; i += 256) atomicAdd(&lcnt[dst[e0 + i] >> NPB_SHIFT], 1);
    __syncthreads();
    for (int i = t; i < nbuk; i += 256)
        if (lcnt[i]) atomicAdd(&gcnt[i], lcnt[i]);
}

// single-block exclusive scan of gcnt[nbuk] -> gbase, gcur
__global__ void scan_kernel(const int* __restrict__ gcnt, int* __restrict__ gbase,
                            int* __restrict__ gcur, int nbuk) {
    __shared__ int sd[256];
    int t = threadIdx.x;
    int v[4], s = 0;
#pragma unroll
    for (int k = 0; k < 4; ++k) {
        int i = 4 * t + k;
        v[k] = (i < nbuk) ? gcnt[i] : 0;
        s += v[k];
    }
    sd[t] = s;
    __syncthreads();
    for (int off = 1; off < 256; off <<= 1) {
        int x = (t >= off) ? sd[t - off] : 0;
        __syncthreads();
        sd[t] += x;
        __syncthreads();
    }
    int run = sd[t] - s;
#pragma unroll
    for (int k = 0; k < 4; ++k) {
        int i = 4 * t + k;
        if (i < nbuk) { gbase[i] = run; gcur[i] = run; }
        run += v[k];
    }
}

// LDS counting-sort of 8192 edges by bucket, bulk-append to global regions
__global__ void binfill_kernel(const int* __restrict__ src, const int* __restrict__ dst,
                               int* __restrict__ gcur, unsigned int* __restrict__ binned,
                               int e, int nbuk) {
    __shared__ int cnt[NBUK_MAX];
    __shared__ int pos[NBUK_MAX];
    __shared__ int gb[NBUK_MAX];
    __shared__ unsigned int sorted[FILL_EDGES];
    __shared__ unsigned short aux[FILL_EDGES];
    __shared__ int stmp[256];

    int t = threadIdx.x;
    int e0 = blockIdx.x * FILL_EDGES;
    int m = min(FILL_EDGES, e - e0);

    for (int i = t; i < nbuk; i += 256) cnt[i] = 0;
    __syncthreads();
    for (int i = t; i < m; i += 256) atomicAdd(&cnt[dst[e0 + i] >> NPB_SHIFT], 1);
    __syncthreads();

    int v[4], s = 0;
#pragma unroll
    for (int k = 0; k < 4; ++k) {
        int i = 4 * t + k;
        v[k] = (i < nbuk) ? cnt[i] : 0;
        s += v[k];
    }
    stmp[t] = s;
    __syncthreads();
    for (int off = 1; off < 256; off <<= 1) {
        int x = (t >= off) ? stmp[t - off] : 0;
        __syncthreads();
        stmp[t] += x;
        __syncthreads();
    }
    int run = stmp[t] - s;
#pragma unroll
    for (int k = 0; k < 4; ++k) {
        int i = 4 * t + k;
        if (i < nbuk) pos[i] = run;
        run += v[k];
    }
    __syncthreads();

    for (int i = t; i < m; i += 256) {
        int d = dst[e0 + i];
        int sv = src[e0 + i];
        int b = d >> NPB_SHIFT;
        int r = atomicAdd(&pos[b], 1);
        sorted[r] = ((unsigned int)(d & (NPB - 1)) << 17) | (unsigned int)sv;
        aux[r] = (unsigned short)b;
    }
    __syncthreads();

    for (int b = t; b < nbuk; b += 256) {
        int c = cnt[b];
        gb[b] = c ? atomicAdd(&gcur[b], c) : 0;
    }
    __syncthreads();

    for (int i = t; i < m; i += 256) {
        int b = aux[i];
        int start = pos[b] - cnt[b];
        binned[gb[b] + (i - start)] = sorted[i];
    }
}

// per-bucket node degree from binned (LDS int atomics) -> dinv = rsqrt(deg+1)
__global__ void bdinv_kernel(const int* __restrict__ gbase, const int* __restrict__ gcnt,
                             const unsigned int* __restrict__ binned,
                             float* __restrict__ dinv, int n) {
    __shared__ int cnt[NPB];
    int t = threadIdx.x;
    int b = blockIdx.x;
    if (t < NPB) cnt[t] = 0;
    __syncthreads();
    const int beg = gbase[b];
    const int cntb = gcnt[b];
    for (int i = t; i < cntb; i += 256) atomicAdd(&cnt[binned[beg + i] >> 17], 1);
    __syncthreads();
    if (t < NPB) {
        int r = (b << NPB_SHIFT) + t;
        if (r < n) dinv[r] = rsqrtf((float)(cnt[t] + 1));
    }
}

// mqc[r][c] = (x[r]·W1[:,c]) * dinv[r], bf16.  32 rows/block staged in
// padded LDS; thread = (row, 4 cols); register-lean, no spills.
#define XLD 132
__global__ void gemm1_kernel(const float* __restrict__ x, const float* __restrict__ W1,
                             const float* __restrict__ dinv,
                             unsigned short* __restrict__ mqc, int n) {
    __shared__ float  Xl[32 * XLD];
    __shared__ float4 Wl4[DIN * 8];

    int t = threadIdx.x;
    for (int i = t; i < DIN * 8; i += 256) Wl4[i] = ((const float4*)W1)[i];

    int rb = blockIdx.x * 32;
    for (int i = t; i < 32 * 32; i += 256) {
        int rr = i >> 5, c4 = i & 31;
        int gr = rb + rr;
        float4 v = make_float4(0.f, 0.f, 0.f, 0.f);
        if (gr < n) v = ((const float4*)x)[(size_t)gr * 32 + c4];
        ((float4*)Xl)[rr * 33 + c4] = v;
    }
    __syncthreads();

    const int lane = t & 7;
    const int row  = t >> 3;
    const float* xrow = &Xl[row * XLD];
    float4 acc = make_float4(0.f, 0.f, 0.f, 0.f);
#pragma unroll
    for (int k = 0; k < DIN; ++k) {
        float xv = xrow[k];
        float4 w = Wl4[k * 8 + lane];
        acc.x += xv * w.x; acc.y += xv * w.y;
        acc.z += xv * w.z; acc.w += xv * w.w;
    }
    int r = rb + row;
    if (r < n) {
        float di = dinv[r];
        ushort4 sv;
        sv.x = f2bf(acc.x * di); sv.y = f2bf(acc.y * di);
        sv.z = f2bf(acc.z * di); sv.w = f2bf(acc.w * di);
        *(ushort4*)&mqc[(size_t)r * DH + 4 * lane] = sv;
    }
}

// one block per bucket.  Per chunk: SINGLE-PASS padded-slot scatter (one
// atomic-return per edge, no count pass, no scan), then transposed register
// gather.  Rank >= PAD goes to a bounded LDS overflow list (slow path,
// normally empty) -> correct for arbitrary degree skew.
__global__ void agg1_kernel(const int* __restrict__ gbase, const int* __restrict__ gcnt,
                            const unsigned int* __restrict__ binned,
                            const unsigned short* __restrict__ mqc,
                            const float* __restrict__ dinv,
                            const float* __restrict__ b1, const float* __restrict__ W2,
                            float2* __restrict__ m2q, int n) {
    __shared__ unsigned int slots[NPB * PAD];   // 24 KB
    __shared__ unsigned int ovf[CHUNK];         // 8 KB
    __shared__ int cur[NPB];
    __shared__ int ovn;

    const int t = threadIdx.x;
    const int b = blockIdx.x;
    const int lane = t & 31;
    const int half = t >> 5;    // 0..7
    const int beg = gbase[b];
    const int cntb = gcnt[b];
    const int r0 = b << NPB_SHIFT;

    float acc[16];
#pragma unroll
    for (int q = 0; q < 16; ++q) acc[q] = 0.0f;

    for (int off = 0; off < cntb; off += CHUNK) {
        const int m = min(CHUNK, cntb - off);

        if (t < NPB) cur[t] = 0;
        if (t == 0) ovn = 0;
        __syncthreads();

        // single-pass scatter: rank via atomic-return, rank<PAD -> slot strip
        for (int i = t; i < m; i += 256) {
            unsigned int en = binned[beg + off + i];
            int dl = (int)(en >> 17);
            int p = atomicAdd(&cur[dl], 1);
            if (p < PAD) slots[dl * PAD + p] = en & 0x1FFFFu;
            else { int p2 = atomicAdd(&ovn, 1); ovf[p2] = en; }
        }
        __syncthreads();

        // transposed gather: u-step outer, 16 node accumulators inner
        int kq[16];
        int maxk = 0;
#pragma unroll
        for (int q = 0; q < 16; ++q) {
            int c = min(cur[q * 8 + half], PAD);
            kq[q] = c;
            maxk = max(maxk, c);
        }
        for (int u = 0; u < maxk; ++u) {
#pragma unroll
            for (int q = 0; q < 16; ++q) {
                int uu = (u < kq[q]) ? u : 0;          // always-written-or-masked
                // mask to 17 bits: unwritten slot garbage stays inside d_ws,
                // value is predicated out below
                int s = (int)(slots[(q * 8 + half) * PAD + uu] & 0x1FFFFu);
                float val = bf2f(mqc[(size_t)s * DH + lane]);
                acc[q] += (u < kq[q]) ? val : 0.0f;
            }
        }

        // overflow slow path (normally ovn == 0)
        int ovcount = ovn;
        for (int i = 0; i < ovcount; ++i) {
            unsigned int en = ovf[i];
            int dl = (int)(en >> 17);
            float val = bf2f(mqc[(size_t)(en & 0x1FFFFu) * DH + lane]);
#pragma unroll
            for (int q = 0; q < 16; ++q)
                acc[q] += (dl == q * 8 + half) ? val : 0.0f;
        }
        __syncthreads();   // protect cur/slots/ovf before next chunk
    }

    // epilogue: self message + ReLU + W2 transform
#pragma unroll
    for (int q = 0; q < 16; ++q) {
        const int j = q * 8 + half;
        const int r = r0 + j;
        if (r < n) {
            float di = dinv[r];
            float a = acc[q] + bf2f(mqc[(size_t)r * DH + lane]);
            float h = fmaxf(di * a + b1[lane], 0.0f);
            float p0 = h * W2[lane * DOUT + 0];
            float p1 = h * W2[lane * DOUT + 1];
#pragma unroll
            for (int o = 16; o > 0; o >>= 1) {
                p0 += __shfl_down(p0, o, 32);
                p1 += __shfl_down(p1, o, 32);
            }
            if (lane == 0) m2q[r] = make_float2(di * p0, di * p1);
        }
    }
}

// one block per bucket: layer-2 aggregate + bias
__global__ void agg2_kernel(const int* __restrict__ gbase, const int* __restrict__ gcnt,
                            const unsigned int* __restrict__ binned,
                            const float2* __restrict__ m2q,
                            const float* __restrict__ dinv, const float* __restrict__ b2,
                            float* __restrict__ out, int n) {
    __shared__ float acc0[NPB], acc1[NPB];
    int t = threadIdx.x;
    int b = blockIdx.x;
    for (int i = t; i < NPB; i += 256) { acc0[i] = 0.f; acc1[i] = 0.f; }
    __syncthreads();

    const int beg = gbase[b];
    const int cntb = gcnt[b];
    for (int i = t; i < cntb; i += 256) {
        unsigned int entry = binned[beg + i];
        int sv = (int)(entry & 0x1FFFFu);
        int dl = (int)(entry >> 17);
        float2 v = m2q[sv];
        atomicAdd(&acc0[dl], v.x);
        atomicAdd(&acc1[dl], v.y);
    }
    __syncthreads();

    int r0 = b << NPB_SHIFT;
    for (int rl = t; rl < NPB; rl += 256) {
        int r = r0 + rl;
        if (r < n) {
            float di = dinv[r];
            float2 self = m2q[r];
            out[(size_t)r * DOUT + 0] = di * (acc0[rl] + self.x) + b2[0];
            out[(size_t)r * DOUT + 1] = di * (acc1[rl] + self.y) + b2[1];
        }
    }
}

extern "C" void kernel_launch(void* const* d_in, const int* in_sizes, int n_in,
                              void* d_out, int out_size, void* d_ws, size_t ws_size,
                              hipStream_t stream) {
    const float* x  = (const float*)d_in[0];
    const int*   ei = (const int*)d_in[1];
    const float* W1 = (const float*)d_in[2];
    const float* b1 = (const float*)d_in[3];
    const float* W2 = (const float*)d_in[4];
    const float* b2 = (const float*)d_in[5];
    float* out = (float*)d_out;

    const int n = in_sizes[0] / DIN;
    const int e = in_sizes[1] / 2;
    const int* src = ei;
    const int* dst = ei + e;
    const int nbuk = (n + NPB - 1) >> NPB_SHIFT;   // 782 for n=100000

    char* ws = (char*)d_ws;
    float* dinv   = (float*)ws;          ws += (size_t)n * 4;
    int* gcnt     = (int*)ws;            ws += NBUK_MAX * 4;
    int* gbase    = (int*)ws;            ws += NBUK_MAX * 4;
    int* gcur     = (int*)ws;            ws += NBUK_MAX * 4;
    unsigned int* binned = (unsigned int*)ws;   ws += (size_t)e * 4;
    unsigned short* mqc  = (unsigned short*)ws; ws += (size_t)n * DH * 2;
    float2* m2q   = (float2*)ws;

    const int B = 256;
    const int fill_blocks = (e + FILL_EDGES - 1) / FILL_EDGES;   // 391

    zero_gcnt_kernel<<<(nbuk + B - 1) / B, B, 0, stream>>>(gcnt, nbuk);
    bukhist_kernel<<<fill_blocks, B, 0, stream>>>(dst, gcnt, e, nbuk);
    scan_kernel<<<1, B, 0, stream>>>(gcnt, gbase, gcur, nbuk);
    binfill_kernel<<<fill_blocks, B, 0, stream>>>(src, dst, gcur, binned, e, nbuk);
    bdinv_kernel<<<nbuk, B, 0, stream>>>(gbase, gcnt, binned, dinv, n);
    gemm1_kernel<<<(n + 31) / 32, B, 0, stream>>>(x, W1, dinv, mqc, n);
    agg1_kernel<<<nbuk, B, 0, stream>>>(gbase, gcnt, binned, mqc, dinv, b1, W2, m2q, n);
    agg2_kernel<<<nbuk, B, 0, stream>>>(gbase, gcnt, binned, m2q, dinv, b2, out, n);
}

// Round 11
// 366.027 us; speedup vs baseline: 1.4007x; 1.4007x over previous
//
#include <hip/hip_runtime.h>
#include <hip/hip_bf16.h>

#define DIN 128
#define DH 32
#define DOUT 2
#define NPB 128            // nodes per bucket
#define NPB_SHIFT 7
#define NBUK_MAX 1024      // supports n <= 131072 (17-bit src packing)
#define FILL_EDGES 8192    // edges per binning block
#define CHUNKB 6144        // agg1 whole-bucket LDS capacity (mean 4096, 32 sigma)

// ---------------------------------------------------------------------------
// workspace (~20.9 MB, budget ~26.8 MB):
//   dinv float[n]; degarr int[n]; gcnt/gbase/gcur int[NBUK_MAX]
//   binned uint[E]: (dst&127)<<17 | src grouped by bucket; after agg1 each
//                   bucket region is node-sorted src-only (fast path)
//   mqc bf16[n*32]: dinv-scaled layer-1 messages;  m2q float2[n]
// ---------------------------------------------------------------------------

__device__ inline unsigned short f2bf(float f) {
    unsigned int u = __float_as_uint(f);
    u = (u + 0x7FFFu + ((u >> 16) & 1u)) >> 16;
    return (unsigned short)u;
}
__device__ inline float bf2f(unsigned short b) {
    return __uint_as_float(((unsigned int)b) << 16);
}

__global__ void zero_gcnt_kernel(int* __restrict__ gcnt, int nbuk) {
    int i = blockIdx.x * blockDim.x + threadIdx.x;
    if (i < nbuk) gcnt[i] = 0;
}

// bucket-level histogram, LDS-staged
__global__ void bukhist_kernel(const int* __restrict__ dst, int* __restrict__ gcnt,
                               int e, int nbuk) {
    __shared__ int lcnt[NBUK_MAX];
    int t = threadIdx.x;
    for (int i = t; i < nbuk; i += 256) lcnt[i] = 0;
    __syncthreads();
    int e0 = blockIdx.x * FILL_EDGES;
    int m = min(FILL_EDGES, e - e0);
    for (int i = t; i < m; i += 256) atomicAdd(&lcnt[dst[e0 + i] >> NPB_SHIFT], 1);
    __syncthreads();
    for (int i = t; i < nbuk; i += 256)
        if (lcnt[i]) atomicAdd(&gcnt[i], lcnt[i]);
}

// single-block exclusive scan of gcnt[nbuk] -> gbase, gcur
__global__ void scan_kernel(const int* __restrict__ gcnt, int* __restrict__ gbase,
                            int* __restrict__ gcur, int nbuk) {
    __shared__ int sd[256];
    int t = threadIdx.x;
    int v[4], s = 0;
#pragma unroll
    for (int k = 0; k < 4; ++k) {
        int i = 4 * t + k;
        v[k] = (i < nbuk) ? gcnt[i] : 0;
        s += v[k];
    }
    sd[t] = s;
    __syncthreads();
    for (int off = 1; off < 256; off <<= 1) {
        int x = (t >= off) ? sd[t - off] : 0;
        __syncthreads();
        sd[t] += x;
        __syncthreads();
    }
    int run = sd[t] - s;
#pragma unroll
    for (int k = 0; k < 4; ++k) {
        int i = 4 * t + k;
        if (i < nbuk) { gbase[i] = run; gcur[i] = run; }
        run += v[k];
    }
}

// LDS counting-sort of 8192 edges by bucket, bulk-append to global regions
__global__ void binfill_kernel(const int* __restrict__ src, const int* __restrict__ dst,
                               int* __restrict__ gcur, unsigned int* __restrict__ binned,
                               int e, int nbuk) {
    __shared__ int cnt[NBUK_MAX];
    __shared__ int pos[NBUK_MAX];
    __shared__ int gb[NBUK_MAX];
    __shared__ unsigned int sorted[FILL_EDGES];
    __shared__ unsigned short aux[FILL_EDGES];
    __shared__ int stmp[256];

    int t = threadIdx.x;
    int e0 = blockIdx.x * FILL_EDGES;
    int m = min(FILL_EDGES, e - e0);

    for (int i = t; i < nbuk; i += 256) cnt[i] = 0;
    __syncthreads();
    for (int i = t; i < m; i += 256) atomicAdd(&cnt[dst[e0 + i] >> NPB_SHIFT], 1);
    __syncthreads();

    int v[4], s = 0;
#pragma unroll
    for (int k = 0; k < 4; ++k) {
        int i = 4 * t + k;
        v[k] = (i < nbuk) ? cnt[i] : 0;
        s += v[k];
    }
    stmp[t] = s;
    __syncthreads();
    for (int off = 1; off < 256; off <<= 1) {
        int x = (t >= off) ? stmp[t - off] : 0;
        __syncthreads();
        stmp[t] += x;
        __syncthreads();
    }
    int run = stmp[t] - s;
#pragma unroll
    for (int k = 0; k < 4; ++k) {
        int i = 4 * t + k;
        if (i < nbuk) pos[i] = run;
        run += v[k];
    }
    __syncthreads();

    for (int i = t; i < m; i += 256) {
        int d = dst[e0 + i];
        int sv = src[e0 + i];
        int b = d >> NPB_SHIFT;
        int r = atomicAdd(&pos[b], 1);
        sorted[r] = ((unsigned int)(d & (NPB - 1)) << 17) | (unsigned int)sv;
        aux[r] = (unsigned short)b;
    }
    __syncthreads();

    for (int b = t; b < nbuk; b += 256) {
        int c = cnt[b];
        gb[b] = c ? atomicAdd(&gcur[b], c) : 0;
    }
    __syncthreads();

    for (int i = t; i < m; i += 256) {
        int b = aux[i];
        int start = pos[b] - cnt[b];
        binned[gb[b] + (i - start)] = sorted[i];
    }
}

// per-bucket node degree from binned -> dinv = rsqrt(deg+1), degarr = deg
__global__ void bdinv_kernel(const int* __restrict__ gbase, const int* __restrict__ gcnt,
                             const unsigned int* __restrict__ binned,
                             float* __restrict__ dinv, int* __restrict__ degarr, int n) {
    __shared__ int cnt[NPB];
    int t = threadIdx.x;
    int b = blockIdx.x;
    if (t < NPB) cnt[t] = 0;
    __syncthreads();
    const int beg = gbase[b];
    const int cntb = gcnt[b];
    for (int i = t; i < cntb; i += 256) atomicAdd(&cnt[binned[beg + i] >> 17], 1);
    __syncthreads();
    if (t < NPB) {
        int r = (b << NPB_SHIFT) + t;
        if (r < n) { dinv[r] = rsqrtf((float)(cnt[t] + 1)); degarr[r] = cnt[t]; }
    }
}

// mqc[r][c] = (x[r]·W1[:,c]) * dinv[r], bf16.  32 rows/block staged in
// padded LDS; thread = (row, 4 cols); register-lean, no spills.
#define XLD 132
__global__ void gemm1_kernel(const float* __restrict__ x, const float* __restrict__ W1,
                             const float* __restrict__ dinv,
                             unsigned short* __restrict__ mqc, int n) {
    __shared__ float  Xl[32 * XLD];
    __shared__ float4 Wl4[DIN * 8];

    int t = threadIdx.x;
    for (int i = t; i < DIN * 8; i += 256) Wl4[i] = ((const float4*)W1)[i];

    int rb = blockIdx.x * 32;
    for (int i = t; i < 32 * 32; i += 256) {
        int rr = i >> 5, c4 = i & 31;
        int gr = rb + rr;
        float4 v = make_float4(0.f, 0.f, 0.f, 0.f);
        if (gr < n) v = ((const float4*)x)[(size_t)gr * 32 + c4];
        ((float4*)Xl)[rr * 33 + c4] = v;
    }
    __syncthreads();

    const int lane = t & 7;
    const int row  = t >> 3;
    const float* xrow = &Xl[row * XLD];
    float4 acc = make_float4(0.f, 0.f, 0.f, 0.f);
#pragma unroll
    for (int k = 0; k < DIN; ++k) {
        float xv = xrow[k];
        float4 w = Wl4[k * 8 + lane];
        acc.x += xv * w.x; acc.y += xv * w.y;
        acc.z += xv * w.z; acc.w += xv * w.w;
    }
    int r = rb + row;
    if (r < n) {
        float di = dinv[r];
        ushort4 sv;
        sv.x = f2bf(acc.x * di); sv.y = f2bf(acc.y * di);
        sv.z = f2bf(acc.z * di); sv.w = f2bf(acc.w * di);
        *(ushort4*)&mqc[(size_t)r * DH + 4 * lane] = sv;
    }
}

// one block per bucket.  FAST PATH (cntb <= CHUNKB, always for this data):
// offsets from degarr scan (no count pass), single scatter (atomic-return),
// round-9 transposed register gather, node-sorted write-back for agg2.
// FALLBACK (huge bucket): round-9 chunked counting sort, no write-back.
__global__ void agg1_kernel(const int* __restrict__ gbase, const int* __restrict__ gcnt,
                            const int* __restrict__ degarr,
                            unsigned int* __restrict__ binned,
                            const unsigned short* __restrict__ mqc,
                            const float* __restrict__ dinv,
                            const float* __restrict__ b1, const float* __restrict__ W2,
                            float2* __restrict__ m2q, int n) {
    __shared__ unsigned int sortedc[CHUNKB];   // 24 KB
    __shared__ int dg[NPB];
    __shared__ int offs[NPB];
    __shared__ int cur[NPB];
    __shared__ int stmp[256];

    const int t = threadIdx.x;
    const int b = blockIdx.x;
    const int lane = t & 31;
    const int half = t >> 5;    // 0..7
    const int beg = gbase[b];
    const int cntb = gcnt[b];
    const int r0 = b << NPB_SHIFT;

    float acc[16];
#pragma unroll
    for (int q = 0; q < 16; ++q) acc[q] = 0.0f;

    if (cntb <= CHUNKB) {
        // ---- fast path ----
        if (t < NPB) {
            int r = r0 + t;
            dg[t] = (r < n) ? degarr[r] : 0;
        }
        __syncthreads();
        int v = (t < NPB) ? dg[t] : 0;
        stmp[t] = v;
        __syncthreads();
        for (int o = 1; o < NPB; o <<= 1) {
            int xx = (t >= o) ? stmp[t - o] : 0;
            __syncthreads();
            stmp[t] += xx;
            __syncthreads();
        }
        if (t < NPB) { offs[t] = stmp[t] - v; cur[t] = stmp[t] - v; }
        __syncthreads();

        // single-pass scatter into node-sorted order
        for (int i = t; i < cntb; i += 256) {
            unsigned int en = binned[beg + i];
            int p = atomicAdd(&cur[en >> 17], 1);
            sortedc[p] = en & 0x1FFFFu;
        }
        __syncthreads();

        // transposed gather (round-9 code, byte-identical structure)
        int e0q[16], kq[16];
        int maxk = 0;
#pragma unroll
        for (int q = 0; q < 16; ++q) {
            int j = q * 8 + half;
            e0q[q] = offs[j];
            kq[q] = dg[j];
            maxk = max(maxk, kq[q]);
        }
        for (int u = 0; u < maxk; ++u) {
#pragma unroll
            for (int q = 0; q < 16; ++q) {
                int idx = min(e0q[q] + u, cntb - 1);
                int s = (int)sortedc[idx];
                float val = bf2f(mqc[(size_t)s * DH + lane]);
                acc[q] += (u < kq[q]) ? val : 0.0f;
            }
        }

        // write node-sorted src-only entries back for agg2 (coalesced)
        for (int i = t; i < cntb; i += 256) binned[beg + i] = sortedc[i];
    } else {
        // ---- fallback: chunked counting sort (round-9), re-reads binned ----
        for (int off = 0; off < cntb; off += CHUNKB) {
            const int m = min(CHUNKB, cntb - off);

            if (t < NPB) cur[t] = 0;
            __syncthreads();
            for (int i = t; i < m; i += 256)
                atomicAdd(&cur[binned[beg + off + i] >> 17], 1);
            __syncthreads();

            int v = (t < NPB) ? cur[t] : 0;
            stmp[t] = v;
            __syncthreads();
            for (int o = 1; o < NPB; o <<= 1) {
                int xx = (t >= o) ? stmp[t - o] : 0;
                __syncthreads();
                stmp[t] += xx;
                __syncthreads();
            }
            if (t < NPB) { dg[t] = v; offs[t] = stmp[t] - v; cur[t] = stmp[t] - v; }
            __syncthreads();

            for (int i = t; i < m; i += 256) {
                unsigned int en = binned[beg + off + i];
                int p = atomicAdd(&cur[en >> 17], 1);
                sortedc[p] = en & 0x1FFFFu;
            }
            __syncthreads();

            int e0q[16], kq[16];
            int maxk = 0;
#pragma unroll
            for (int q = 0; q < 16; ++q) {
                int j = q * 8 + half;
                e0q[q] = offs[j];
                kq[q] = dg[j];
                maxk = max(maxk, kq[q]);
            }
            for (int u = 0; u < maxk; ++u) {
#pragma unroll
                for (int q = 0; q < 16; ++q) {
                    int idx = min(e0q[q] + u, m - 1);
                    int s = (int)sortedc[idx];
                    float val = bf2f(mqc[(size_t)s * DH + lane]);
                    acc[q] += (u < kq[q]) ? val : 0.0f;
                }
            }
            __syncthreads();
        }
    }

    // epilogue: self message + ReLU + W2 transform
#pragma unroll
    for (int q = 0; q < 16; ++q) {
        const int j = q * 8 + half;
        const int r = r0 + j;
        if (r < n) {
            float di = dinv[r];
            float a = acc[q] + bf2f(mqc[(size_t)r * DH + lane]);
            float h = fmaxf(di * a + b1[lane], 0.0f);
            float p0 = h * W2[lane * DOUT + 0];
            float p1 = h * W2[lane * DOUT + 1];
#pragma unroll
            for (int o = 16; o > 0; o >>= 1) {
                p0 += __shfl_down(p0, o, 32);
                p1 += __shfl_down(p1, o, 32);
            }
            if (lane == 0) m2q[r] = make_float2(di * p0, di * p1);
        }
    }
}

// one block per bucket.  FAST PATH: binned is node-sorted -> atomic-free
// gather, 2 threads per node (split run), shuffle-combine.  FALLBACK: LDS
// fp32 atomics on unsorted entries.
__global__ void agg2_kernel(const int* __restrict__ gbase, const int* __restrict__ gcnt,
                            const int* __restrict__ degarr,
                            const unsigned int* __restrict__ binned,
                            const float2* __restrict__ m2q,
                            const float* __restrict__ dinv, const float* __restrict__ b2,
                            float* __restrict__ out, int n) {
    __shared__ int dg[NPB];
    __shared__ int offs[NPB];
    __shared__ int stmp[256];
    __shared__ float a0s[NPB], a1s[NPB];

    const int t = threadIdx.x;
    const int b = blockIdx.x;
    const int beg = gbase[b];
    const int cntb = gcnt[b];
    const int r0 = b << NPB_SHIFT;

    if (cntb <= CHUNKB) {
        if (t < NPB) {
            int r = r0 + t;
            dg[t] = (r < n) ? degarr[r] : 0;
        }
        __syncthreads();
        int v = (t < NPB) ? dg[t] : 0;
        stmp[t] = v;
        __syncthreads();
        for (int o = 1; o < NPB; o <<= 1) {
            int xx = (t >= o) ? stmp[t - o] : 0;
            __syncthreads();
            stmp[t] += xx;
            __syncthreads();
        }
        if (t < NPB) offs[t] = stmp[t] - v;
        __syncthreads();

        int j = t >> 1, hf = t & 1;
        int d = dg[j], o = offs[j];
        int lo = o + (hf ? (d >> 1) : 0);
        int hi = o + (hf ? d : (d >> 1));
        float a0 = 0.f, a1 = 0.f;
        for (int i = lo; i < hi; ++i) {
            int s = (int)(binned[beg + i] & 0x1FFFFu);
            float2 vv = m2q[s];
            a0 += vv.x; a1 += vv.y;
        }
        a0 += __shfl_down(a0, 1, 2);
        a1 += __shfl_down(a1, 1, 2);
        if (hf == 0) {
            int r = r0 + j;
            if (r < n) {
                float di = dinv[r];
                float2 self = m2q[r];
                out[(size_t)r * DOUT + 0] = di * (a0 + self.x) + b2[0];
                out[(size_t)r * DOUT + 1] = di * (a1 + self.y) + b2[1];
            }
        }
    } else {
        for (int i = t; i < NPB; i += 256) { a0s[i] = 0.f; a1s[i] = 0.f; }
        __syncthreads();
        for (int i = t; i < cntb; i += 256) {
            unsigned int entry = binned[beg + i];
            int sv = (int)(entry & 0x1FFFFu);
            int dl = (int)(entry >> 17);
            float2 vv = m2q[sv];
            atomicAdd(&a0s[dl], vv.x);
            atomicAdd(&a1s[dl], vv.y);
        }
        __syncthreads();
        for (int rl = t; rl < NPB; rl += 256) {
            int r = r0 + rl;
            if (r < n) {
                float di = dinv[r];
                float2 self = m2q[r];
                out[(size_t)r * DOUT + 0] = di * (a0s[rl] + self.x) + b2[0];
                out[(size_t)r * DOUT + 1] = di * (a1s[rl] + self.y) + b2[1];
            }
        }
    }
}

extern "C" void kernel_launch(void* const* d_in, const int* in_sizes, int n_in,
                              void* d_out, int out_size, void* d_ws, size_t ws_size,
                              hipStream_t stream) {
    const float* x  = (const float*)d_in[0];
    const int*   ei = (const int*)d_in[1];
    const float* W1 = (const float*)d_in[2];
    const float* b1 = (const float*)d_in[3];
    const float* W2 = (const float*)d_in[4];
    const float* b2 = (const float*)d_in[5];
    float* out = (float*)d_out;

    const int n = in_sizes[0] / DIN;
    const int e = in_sizes[1] / 2;
    const int* src = ei;
    const int* dst = ei + e;
    const int nbuk = (n + NPB - 1) >> NPB_SHIFT;   // 782 for n=100000

    char* ws = (char*)d_ws;
    float* dinv   = (float*)ws;          ws += (size_t)n * 4;
    int* degarr   = (int*)ws;            ws += (size_t)n * 4;
    int* gcnt     = (int*)ws;            ws += NBUK_MAX * 4;
    int* gbase    = (int*)ws;            ws += NBUK_MAX * 4;
    int* gcur     = (int*)ws;            ws += NBUK_MAX * 4;
    unsigned int* binned = (unsigned int*)ws;   ws += (size_t)e * 4;
    unsigned short* mqc  = (unsigned short*)ws; ws += (size_t)n * DH * 2;
    float2* m2q   = (float2*)ws;

    const int B = 256;
    const int fill_blocks = (e + FILL_EDGES - 1) / FILL_EDGES;   // 391

    zero_gcnt_kernel<<<(nbuk + B - 1) / B, B, 0, stream>>>(gcnt, nbuk);
    bukhist_kernel<<<fill_blocks, B, 0, stream>>>(dst, gcnt, e, nbuk);
    scan_kernel<<<1, B, 0, stream>>>(gcnt, gbase, gcur, nbuk);
    binfill_kernel<<<fill_blocks, B, 0, stream>>>(src, dst, gcur, binned, e, nbuk);
    bdinv_kernel<<<nbuk, B, 0, stream>>>(gbase, gcnt, binned, dinv, degarr, n);
    gemm1_kernel<<<(n + 31) / 32, B, 0, stream>>>(x, W1, dinv, mqc, n);
    agg1_kernel<<<nbuk, B, 0, stream>>>(gbase, gcnt, degarr, binned, mqc, dinv, b1, W2, m2q, n);
    agg2_kernel<<<nbuk, B, 0, stream>>>(gbase, gcnt, degarr, binned, m2q, dinv, b2, out, n);
}

// Round 12
// 281.111 us; speedup vs baseline: 1.8238x; 1.3021x over previous
//
#include <hip/hip_runtime.h>
#include <hip/hip_bf16.h>

#define DIN 128
#define DH 32
#define DOUT 2
#define NPB 128            // nodes per bucket
#define NPB_SHIFT 7
#define NBUK_MAX 1024      // supports n <= 131072 (17-bit src packing)
#define FILL_EDGES 8192    // edges per binning block
#define CHUNKB 6144        // agg1 whole-bucket LDS capacity (mean 4096, 32 sigma)

// ---------------------------------------------------------------------------
// workspace (~20.9 MB, budget ~26.8 MB):
//   dinv float[n]; degarr int[n]; gcnt/gbase/gcur int[NBUK_MAX]
//   binned uint[E]: (dst&127)<<17 | src grouped by bucket; after agg1 each
//                   bucket region is node-sorted src-only (fast path)
//   mqc bf16[n*32]: dinv-scaled layer-1 messages;  m2q float2[n]
// ---------------------------------------------------------------------------

__device__ inline unsigned short f2bf(float f) {
    unsigned int u = __float_as_uint(f);
    u = (u + 0x7FFFu + ((u >> 16) & 1u)) >> 16;
    return (unsigned short)u;
}
__device__ inline float bf2f(unsigned short b) {
    return __uint_as_float(((unsigned int)b) << 16);
}

__global__ void zero_gcnt_kernel(int* __restrict__ gcnt, int nbuk) {
    int i = blockIdx.x * blockDim.x + threadIdx.x;
    if (i < nbuk) gcnt[i] = 0;
}

// bucket-level histogram, LDS-staged
__global__ void bukhist_kernel(const int* __restrict__ dst, int* __restrict__ gcnt,
                               int e, int nbuk) {
    __shared__ int lcnt[NBUK_MAX];
    int t = threadIdx.x;
    for (int i = t; i < nbuk; i += 256) lcnt[i] = 0;
    __syncthreads();
    int e0 = blockIdx.x * FILL_EDGES;
    int m = min(FILL_EDGES, e - e0);
    for (int i = t; i < m; i += 256) atomicAdd(&lcnt[dst[e0 + i] >> NPB_SHIFT], 1);
    __syncthreads();
    for (int i = t; i < nbuk; i += 256)
        if (lcnt[i]) atomicAdd(&gcnt[i], lcnt[i]);
}

// single-block exclusive scan of gcnt[nbuk] -> gbase, gcur
__global__ void scan_kernel(const int* __restrict__ gcnt, int* __restrict__ gbase,
                            int* __restrict__ gcur, int nbuk) {
    __shared__ int sd[256];
    int t = threadIdx.x;
    int v[4], s = 0;
#pragma unroll
    for (int k = 0; k < 4; ++k) {
        int i = 4 * t + k;
        v[k] = (i < nbuk) ? gcnt[i] : 0;
        s += v[k];
    }
    sd[t] = s;
    __syncthreads();
    for (int off = 1; off < 256; off <<= 1) {
        int x = (t >= off) ? sd[t - off] : 0;
        __syncthreads();
        sd[t] += x;
        __syncthreads();
    }
    int run = sd[t] - s;
#pragma unroll
    for (int k = 0; k < 4; ++k) {
        int i = 4 * t + k;
        if (i < nbuk) { gbase[i] = run; gcur[i] = run; }
        run += v[k];
    }
}

// LDS counting-sort of 8192 edges by bucket, bulk-append to global regions
__global__ void binfill_kernel(const int* __restrict__ src, const int* __restrict__ dst,
                               int* __restrict__ gcur, unsigned int* __restrict__ binned,
                               int e, int nbuk) {
    __shared__ int cnt[NBUK_MAX];
    __shared__ int pos[NBUK_MAX];
    __shared__ int gb[NBUK_MAX];
    __shared__ unsigned int sorted[FILL_EDGES];
    __shared__ unsigned short aux[FILL_EDGES];
    __shared__ int stmp[256];

    int t = threadIdx.x;
    int e0 = blockIdx.x * FILL_EDGES;
    int m = min(FILL_EDGES, e - e0);

    for (int i = t; i < nbuk; i += 256) cnt[i] = 0;
    __syncthreads();
    for (int i = t; i < m; i += 256) atomicAdd(&cnt[dst[e0 + i] >> NPB_SHIFT], 1);
    __syncthreads();

    int v[4], s = 0;
#pragma unroll
    for (int k = 0; k < 4; ++k) {
        int i = 4 * t + k;
        v[k] = (i < nbuk) ? cnt[i] : 0;
        s += v[k];
    }
    stmp[t] = s;
    __syncthreads();
    for (int off = 1; off < 256; off <<= 1) {
        int x = (t >= off) ? stmp[t - off] : 0;
        __syncthreads();
        stmp[t] += x;
        __syncthreads();
    }
    int run = stmp[t] - s;
#pragma unroll
    for (int k = 0; k < 4; ++k) {
        int i = 4 * t + k;
        if (i < nbuk) pos[i] = run;
        run += v[k];
    }
    __syncthreads();

    for (int i = t; i < m; i += 256) {
        int d = dst[e0 + i];
        int sv = src[e0 + i];
        int b = d >> NPB_SHIFT;
        int r = atomicAdd(&pos[b], 1);
        sorted[r] = ((unsigned int)(d & (NPB - 1)) << 17) | (unsigned int)sv;
        aux[r] = (unsigned short)b;
    }
    __syncthreads();

    for (int b = t; b < nbuk; b += 256) {
        int c = cnt[b];
        gb[b] = c ? atomicAdd(&gcur[b], c) : 0;
    }
    __syncthreads();

    for (int i = t; i < m; i += 256) {
        int b = aux[i];
        int start = pos[b] - cnt[b];
        binned[gb[b] + (i - start)] = sorted[i];
    }
}

// per-bucket node degree from binned -> dinv = rsqrt(deg+1), degarr = deg
__global__ void bdinv_kernel(const int* __restrict__ gbase, const int* __restrict__ gcnt,
                             const unsigned int* __restrict__ binned,
                             float* __restrict__ dinv, int* __restrict__ degarr, int n) {
    __shared__ int cnt[NPB];
    int t = threadIdx.x;
    int b = blockIdx.x;
    if (t < NPB) cnt[t] = 0;
    __syncthreads();
    const int beg = gbase[b];
    const int cntb = gcnt[b];
    for (int i = t; i < cntb; i += 256) atomicAdd(&cnt[binned[beg + i] >> 17], 1);
    __syncthreads();
    if (t < NPB) {
        int r = (b << NPB_SHIFT) + t;
        if (r < n) { dinv[r] = rsqrtf((float)(cnt[t] + 1)); degarr[r] = cnt[t]; }
    }
}

// mqc[r][c] = (x[r]·W1[:,c]) * dinv[r], bf16.  32 rows/block staged in
// padded LDS; thread = (row, 4 cols); register-lean, no spills.
#define XLD 132
__global__ void gemm1_kernel(const float* __restrict__ x, const float* __restrict__ W1,
                             const float* __restrict__ dinv,
                             unsigned short* __restrict__ mqc, int n) {
    __shared__ float  Xl[32 * XLD];
    __shared__ float4 Wl4[DIN * 8];

    int t = threadIdx.x;
    for (int i = t; i < DIN * 8; i += 256) Wl4[i] = ((const float4*)W1)[i];

    int rb = blockIdx.x * 32;
    for (int i = t; i < 32 * 32; i += 256) {
        int rr = i >> 5, c4 = i & 31;
        int gr = rb + rr;
        float4 v = make_float4(0.f, 0.f, 0.f, 0.f);
        if (gr < n) v = ((const float4*)x)[(size_t)gr * 32 + c4];
        ((float4*)Xl)[rr * 33 + c4] = v;
    }
    __syncthreads();

    const int lane = t & 7;
    const int row  = t >> 3;
    const float* xrow = &Xl[row * XLD];
    float4 acc = make_float4(0.f, 0.f, 0.f, 0.f);
#pragma unroll
    for (int k = 0; k < DIN; ++k) {
        float xv = xrow[k];
        float4 w = Wl4[k * 8 + lane];
        acc.x += xv * w.x; acc.y += xv * w.y;
        acc.z += xv * w.z; acc.w += xv * w.w;
    }
    int r = rb + row;
    if (r < n) {
        float di = dinv[r];
        ushort4 sv;
        sv.x = f2bf(acc.x * di); sv.y = f2bf(acc.y * di);
        sv.z = f2bf(acc.z * di); sv.w = f2bf(acc.w * di);
        *(ushort4*)&mqc[(size_t)r * DH + 4 * lane] = sv;
    }
}

// one block per bucket.  __launch_bounds__(256,3): occupancy is LDS/grid-
// capped at ~3 blocks/CU anyway; this lifts the VGPR budget (~170) so the
// 16-deep independent-load gather pipeline is never serialized by the
// allocator (rounds 10/11: VGPR squeezed to 32/40 -> 3x slower gather).
__global__ void __launch_bounds__(256, 3)
agg1_kernel(const int* __restrict__ gbase, const int* __restrict__ gcnt,
            const int* __restrict__ degarr,
            unsigned int* __restrict__ binned,
            const unsigned short* __restrict__ mqc,
            const float* __restrict__ dinv,
            const float* __restrict__ b1, const float* __restrict__ W2,
            float2* __restrict__ m2q, int n) {
    __shared__ unsigned int sortedc[CHUNKB];   // 24 KB
    __shared__ int dg[NPB];
    __shared__ int offs[NPB];
    __shared__ int cur[NPB];
    __shared__ int stmp[256];

    const int t = threadIdx.x;
    const int b = blockIdx.x;
    const int lane = t & 31;
    const int half = t >> 5;    // 0..7
    const int beg = gbase[b];
    const int cntb = gcnt[b];
    const int r0 = b << NPB_SHIFT;

    float acc[16];
#pragma unroll
    for (int q = 0; q < 16; ++q) acc[q] = 0.0f;

    if (cntb <= CHUNKB) {
        // ---- fast path ----
        if (t < NPB) {
            int r = r0 + t;
            dg[t] = (r < n) ? degarr[r] : 0;
        }
        __syncthreads();
        int v = (t < NPB) ? dg[t] : 0;
        stmp[t] = v;
        __syncthreads();
        for (int o = 1; o < NPB; o <<= 1) {
            int xx = (t >= o) ? stmp[t - o] : 0;
            __syncthreads();
            stmp[t] += xx;
            __syncthreads();
        }
        if (t < NPB) { offs[t] = stmp[t] - v; cur[t] = stmp[t] - v; }
        __syncthreads();

        // single-pass scatter into node-sorted order
        for (int i = t; i < cntb; i += 256) {
            unsigned int en = binned[beg + i];
            int p = atomicAdd(&cur[en >> 17], 1);
            sortedc[p] = en & 0x1FFFFu;
        }
        __syncthreads();

        // transposed gather: explicit prefetch batch -> accumulate
        int e0q[16], kq[16];
        int maxk = 0;
#pragma unroll
        for (int q = 0; q < 16; ++q) {
            int j = q * 8 + half;
            e0q[q] = offs[j];
            kq[q] = dg[j];
            maxk = max(maxk, kq[q]);
        }
        for (int u = 0; u < maxk; ++u) {
            float val[16];
#pragma unroll
            for (int q = 0; q < 16; ++q) {
                int idx = min(e0q[q] + u, cntb - 1);
                int s = (int)sortedc[idx];
                val[q] = bf2f(mqc[(size_t)s * DH + lane]);
            }
#pragma unroll
            for (int q = 0; q < 16; ++q)
                acc[q] += (u < kq[q]) ? val[q] : 0.0f;
        }

        // write node-sorted src-only entries back for agg2 (coalesced)
        for (int i = t; i < cntb; i += 256) binned[beg + i] = sortedc[i];
    } else {
        // ---- fallback: chunked counting sort (round-9), re-reads binned ----
        for (int off = 0; off < cntb; off += CHUNKB) {
            const int m = min(CHUNKB, cntb - off);

            if (t < NPB) cur[t] = 0;
            __syncthreads();
            for (int i = t; i < m; i += 256)
                atomicAdd(&cur[binned[beg + off + i] >> 17], 1);
            __syncthreads();

            int v = (t < NPB) ? cur[t] : 0;
            stmp[t] = v;
            __syncthreads();
            for (int o = 1; o < NPB; o <<= 1) {
                int xx = (t >= o) ? stmp[t - o] : 0;
                __syncthreads();
                stmp[t] += xx;
                __syncthreads();
            }
            if (t < NPB) { dg[t] = v; offs[t] = stmp[t] - v; cur[t] = stmp[t] - v; }
            __syncthreads();

            for (int i = t; i < m; i += 256) {
                unsigned int en = binned[beg + off + i];
                int p = atomicAdd(&cur[en >> 17], 1);
                sortedc[p] = en & 0x1FFFFu;
            }
            __syncthreads();

            int e0q[16], kq[16];
            int maxk = 0;
#pragma unroll
            for (int q = 0; q < 16; ++q) {
                int j = q * 8 + half;
                e0q[q] = offs[j];
                kq[q] = dg[j];
                maxk = max(maxk, kq[q]);
            }
            for (int u = 0; u < maxk; ++u) {
                float val[16];
#pragma unroll
                for (int q = 0; q < 16; ++q) {
                    int idx = min(e0q[q] + u, m - 1);
                    int s = (int)sortedc[idx];
                    val[q] = bf2f(mqc[(size_t)s * DH + lane]);
                }
#pragma unroll
                for (int q = 0; q < 16; ++q)
                    acc[q] += (u < kq[q]) ? val[q] : 0.0f;
            }
            __syncthreads();
        }
    }

    // epilogue: self message + ReLU + W2 transform
#pragma unroll
    for (int q = 0; q < 16; ++q) {
        const int j = q * 8 + half;
        const int r = r0 + j;
        if (r < n) {
            float di = dinv[r];
            float a = acc[q] + bf2f(mqc[(size_t)r * DH + lane]);
            float h = fmaxf(di * a + b1[lane], 0.0f);
            float p0 = h * W2[lane * DOUT + 0];
            float p1 = h * W2[lane * DOUT + 1];
#pragma unroll
            for (int o = 16; o > 0; o >>= 1) {
                p0 += __shfl_down(p0, o, 32);
                p1 += __shfl_down(p1, o, 32);
            }
            if (lane == 0) m2q[r] = make_float2(di * p0, di * p1);
        }
    }
}

// one block per bucket.  FAST PATH: binned is node-sorted -> atomic-free
// gather, 2 threads per node (split run), shuffle-combine.  FALLBACK: LDS
// fp32 atomics on unsorted entries.
__global__ void agg2_kernel(const int* __restrict__ gbase, const int* __restrict__ gcnt,
                            const int* __restrict__ degarr,
                            const unsigned int* __restrict__ binned,
                            const float2* __restrict__ m2q,
                            const float* __restrict__ dinv, const float* __restrict__ b2,
                            float* __restrict__ out, int n) {
    __shared__ int dg[NPB];
    __shared__ int offs[NPB];
    __shared__ int stmp[256];
    __shared__ float a0s[NPB], a1s[NPB];

    const int t = threadIdx.x;
    const int b = blockIdx.x;
    const int beg = gbase[b];
    const int cntb = gcnt[b];
    const int r0 = b << NPB_SHIFT;

    if (cntb <= CHUNKB) {
        if (t < NPB) {
            int r = r0 + t;
            dg[t] = (r < n) ? degarr[r] : 0;
        }
        __syncthreads();
        int v = (t < NPB) ? dg[t] : 0;
        stmp[t] = v;
        __syncthreads();
        for (int o = 1; o < NPB; o <<= 1) {
            int xx = (t >= o) ? stmp[t - o] : 0;
            __syncthreads();
            stmp[t] += xx;
            __syncthreads();
        }
        if (t < NPB) offs[t] = stmp[t] - v;
        __syncthreads();

        int j = t >> 1, hf = t & 1;
        int d = dg[j], o = offs[j];
        int lo = o + (hf ? (d >> 1) : 0);
        int hi = o + (hf ? d : (d >> 1));
        float a0 = 0.f, a1 = 0.f;
        for (int i = lo; i < hi; ++i) {
            int s = (int)(binned[beg + i] & 0x1FFFFu);
            float2 vv = m2q[s];
            a0 += vv.x; a1 += vv.y;
        }
        a0 += __shfl_down(a0, 1, 2);
        a1 += __shfl_down(a1, 1, 2);
        if (hf == 0) {
            int r = r0 + j;
            if (r < n) {
                float di = dinv[r];
                float2 self = m2q[r];
                out[(size_t)r * DOUT + 0] = di * (a0 + self.x) + b2[0];
                out[(size_t)r * DOUT + 1] = di * (a1 + self.y) + b2[1];
            }
        }
    } else {
        for (int i = t; i < NPB; i += 256) { a0s[i] = 0.f; a1s[i] = 0.f; }
        __syncthreads();
        for (int i = t; i < cntb; i += 256) {
            unsigned int entry = binned[beg + i];
            int sv = (int)(entry & 0x1FFFFu);
            int dl = (int)(entry >> 17);
            float2 vv = m2q[sv];
            atomicAdd(&a0s[dl], vv.x);
            atomicAdd(&a1s[dl], vv.y);
        }
        __syncthreads();
        for (int rl = t; rl < NPB; rl += 256) {
            int r = r0 + rl;
            if (r < n) {
                float di = dinv[r];
                float2 self = m2q[r];
                out[(size_t)r * DOUT + 0] = di * (a0s[rl] + self.x) + b2[0];
                out[(size_t)r * DOUT + 1] = di * (a1s[rl] + self.y) + b2[1];
            }
        }
    }
}

extern "C" void kernel_launch(void* const* d_in, const int* in_sizes, int n_in,
                              void* d_out, int out_size, void* d_ws, size_t ws_size,
                              hipStream_t stream) {
    const float* x  = (const float*)d_in[0];
    const int*   ei = (const int*)d_in[1];
    const float* W1 = (const float*)d_in[2];
    const float* b1 = (const float*)d_in[3];
    const float* W2 = (const float*)d_in[4];
    const float* b2 = (const float*)d_in[5];
    float* out = (float*)d_out;

    const int n = in_sizes[0] / DIN;
    const int e = in_sizes[1] / 2;
    const int* src = ei;
    const int* dst = ei + e;
    const int nbuk = (n + NPB - 1) >> NPB_SHIFT;   // 782 for n=100000

    char* ws = (char*)d_ws;
    float* dinv   = (float*)ws;          ws += (size_t)n * 4;
    int* degarr   = (int*)ws;            ws += (size_t)n * 4;
    int* gcnt     = (int*)ws;            ws += NBUK_MAX * 4;
    int* gbase    = (int*)ws;            ws += NBUK_MAX * 4;
    int* gcur     = (int*)ws;            ws += NBUK_MAX * 4;
    unsigned int* binned = (unsigned int*)ws;   ws += (size_t)e * 4;
    unsigned short* mqc  = (unsigned short*)ws; ws += (size_t)n * DH * 2;
    float2* m2q   = (float2*)ws;

    const int B = 256;
    const int fill_blocks = (e + FILL_EDGES - 1) / FILL_EDGES;   // 391

    zero_gcnt_kernel<<<(nbuk + B - 1) / B, B, 0, stream>>>(gcnt, nbuk);
    bukhist_kernel<<<fill_blocks, B, 0, stream>>>(dst, gcnt, e, nbuk);
    scan_kernel<<<1, B, 0, stream>>>(gcnt, gbase, gcur, nbuk);
    binfill_kernel<<<fill_blocks, B, 0, stream>>>(src, dst, gcur, binned, e, nbuk);
    bdinv_kernel<<<nbuk, B, 0, stream>>>(gbase, gcnt, binned, dinv, degarr, n);
    gemm1_kernel<<<(n + 31) / 32, B, 0, stream>>>(x, W1, dinv, mqc, n);
    agg1_kernel<<<nbuk, B, 0, stream>>>(gbase, gcnt, degarr, binned, mqc, dinv, b1, W2, m2q, n);
    agg2_kernel<<<nbuk, B, 0, stream>>>(gbase, gcnt, degarr, binned, m2q, dinv, b2, out, n);
}

// Round 13
// 248.605 us; speedup vs baseline: 2.0623x; 1.1308x over previous
//
#include <hip/hip_runtime.h>
#include <hip/hip_bf16.h>

#define DIN 128
#define DH 32
#define DOUT 2
#define NPB 128            // nodes per bucket
#define NPB_SHIFT 7
#define NBUK_MAX 1024      // supports n <= 131072 (17-bit src packing)
#define FILL_EDGES 8192    // edges per binning block
#define CHUNKB 8192        // agg1 padded-LDS capacity (padded mean ~5.4K)

// ---------------------------------------------------------------------------
// workspace (~20.9 MB, budget ~26.8 MB):
//   dinv float[n]; degarr int[n]; gcnt/gbase/gcur int[NBUK_MAX]
//   binned uint[E]: (dst&127)<<17 | src grouped by bucket; after agg1 each
//                   bucket region is node-sorted src-only (fast path)
//   mqc bf16[(n+1)*32]: dinv-scaled layer-1 messages + zero sentinel row n
//   m2q float2[n]
// ---------------------------------------------------------------------------

__device__ inline unsigned short f2bf(float f) {
    unsigned int u = __float_as_uint(f);
    u = (u + 0x7FFFu + ((u >> 16) & 1u)) >> 16;
    return (unsigned short)u;
}
__device__ inline float bf2f(unsigned short b) {
    return __uint_as_float(((unsigned int)b) << 16);
}
__device__ inline float bfLO(unsigned int w) { return __uint_as_float(w << 16); }
__device__ inline float bfHI(unsigned int w) { return __uint_as_float(w & 0xFFFF0000u); }

__global__ void zero_gcnt_kernel(int* __restrict__ gcnt, int nbuk) {
    int i = blockIdx.x * blockDim.x + threadIdx.x;
    if (i < nbuk) gcnt[i] = 0;
}

// bucket-level histogram, LDS-staged
__global__ void bukhist_kernel(const int* __restrict__ dst, int* __restrict__ gcnt,
                               int e, int nbuk) {
    __shared__ int lcnt[NBUK_MAX];
    int t = threadIdx.x;
    for (int i = t; i < nbuk; i += 256) lcnt[i] = 0;
    __syncthreads();
    int e0 = blockIdx.x * FILL_EDGES;
    int m = min(FILL_EDGES, e - e0);
    for (int i = t; i < m; i += 256) atomicAdd(&lcnt[dst[e0 + i] >> NPB_SHIFT], 1);
    __syncthreads();
    for (int i = t; i < nbuk; i += 256)
        if (lcnt[i]) atomicAdd(&gcnt[i], lcnt[i]);
}

// single-block exclusive scan of gcnt[nbuk] -> gbase, gcur; also zeroes the
// mqc sentinel row n (gemm1 never writes it; agg1 reads it for padded slots)
__global__ void scan_kernel(const int* __restrict__ gcnt, int* __restrict__ gbase,
                            int* __restrict__ gcur, int nbuk,
                            unsigned short* __restrict__ mqc, int n) {
    __shared__ int sd[256];
    int t = threadIdx.x;
    if (t < 16) ((unsigned int*)(mqc + (size_t)n * DH))[t] = 0u;
    int v[4], s = 0;
#pragma unroll
    for (int k = 0; k < 4; ++k) {
        int i = 4 * t + k;
        v[k] = (i < nbuk) ? gcnt[i] : 0;
        s += v[k];
    }
    sd[t] = s;
    __syncthreads();
    for (int off = 1; off < 256; off <<= 1) {
        int x = (t >= off) ? sd[t - off] : 0;
        __syncthreads();
        sd[t] += x;
        __syncthreads();
    }
    int run = sd[t] - s;
#pragma unroll
    for (int k = 0; k < 4; ++k) {
        int i = 4 * t + k;
        if (i < nbuk) { gbase[i] = run; gcur[i] = run; }
        run += v[k];
    }
}

// LDS counting-sort of 8192 edges by bucket, bulk-append to global regions
__global__ void binfill_kernel(const int* __restrict__ src, const int* __restrict__ dst,
                               int* __restrict__ gcur, unsigned int* __restrict__ binned,
                               int e, int nbuk) {
    __shared__ int cnt[NBUK_MAX];
    __shared__ int pos[NBUK_MAX];
    __shared__ int gb[NBUK_MAX];
    __shared__ unsigned int sorted[FILL_EDGES];
    __shared__ unsigned short aux[FILL_EDGES];
    __shared__ int stmp[256];

    int t = threadIdx.x;
    int e0 = blockIdx.x * FILL_EDGES;
    int m = min(FILL_EDGES, e - e0);

    for (int i = t; i < nbuk; i += 256) cnt[i] = 0;
    __syncthreads();
    for (int i = t; i < m; i += 256) atomicAdd(&cnt[dst[e0 + i] >> NPB_SHIFT], 1);
    __syncthreads();

    int v[4], s = 0;
#pragma unroll
    for (int k = 0; k < 4; ++k) {
        int i = 4 * t + k;
        v[k] = (i < nbuk) ? cnt[i] : 0;
        s += v[k];
    }
    stmp[t] = s;
    __syncthreads();
    for (int off = 1; off < 256; off <<= 1) {
        int x = (t >= off) ? stmp[t - off] : 0;
        __syncthreads();
        stmp[t] += x;
        __syncthreads();
    }
    int run = stmp[t] - s;
#pragma unroll
    for (int k = 0; k < 4; ++k) {
        int i = 4 * t + k;
        if (i < nbuk) pos[i] = run;
        run += v[k];
    }
    __syncthreads();

    for (int i = t; i < m; i += 256) {
        int d = dst[e0 + i];
        int sv = src[e0 + i];
        int b = d >> NPB_SHIFT;
        int r = atomicAdd(&pos[b], 1);
        sorted[r] = ((unsigned int)(d & (NPB - 1)) << 17) | (unsigned int)sv;
        aux[r] = (unsigned short)b;
    }
    __syncthreads();

    for (int b = t; b < nbuk; b += 256) {
        int c = cnt[b];
        gb[b] = c ? atomicAdd(&gcur[b], c) : 0;
    }
    __syncthreads();

    for (int i = t; i < m; i += 256) {
        int b = aux[i];
        int start = pos[b] - cnt[b];
        binned[gb[b] + (i - start)] = sorted[i];
    }
}

// per-bucket node degree from binned -> dinv = rsqrt(deg+1), degarr = deg
__global__ void bdinv_kernel(const int* __restrict__ gbase, const int* __restrict__ gcnt,
                             const unsigned int* __restrict__ binned,
                             float* __restrict__ dinv, int* __restrict__ degarr, int n) {
    __shared__ int cnt[NPB];
    int t = threadIdx.x;
    int b = blockIdx.x;
    if (t < NPB) cnt[t] = 0;
    __syncthreads();
    const int beg = gbase[b];
    const int cntb = gcnt[b];
    for (int i = t; i < cntb; i += 256) atomicAdd(&cnt[binned[beg + i] >> 17], 1);
    __syncthreads();
    if (t < NPB) {
        int r = (b << NPB_SHIFT) + t;
        if (r < n) { dinv[r] = rsqrtf((float)(cnt[t] + 1)); degarr[r] = cnt[t]; }
    }
}

// mqc[r][c] = (x[r]·W1[:,c]) * dinv[r], bf16.  32 rows/block staged in
// padded LDS; thread = (row, 4 cols); register-lean, no spills.
#define XLD 132
__global__ void gemm1_kernel(const float* __restrict__ x, const float* __restrict__ W1,
                             const float* __restrict__ dinv,
                             unsigned short* __restrict__ mqc, int n) {
    __shared__ float  Xl[32 * XLD];
    __shared__ float4 Wl4[DIN * 8];

    int t = threadIdx.x;
    for (int i = t; i < DIN * 8; i += 256) Wl4[i] = ((const float4*)W1)[i];

    int rb = blockIdx.x * 32;
    for (int i = t; i < 32 * 32; i += 256) {
        int rr = i >> 5, c4 = i & 31;
        int gr = rb + rr;
        float4 v = make_float4(0.f, 0.f, 0.f, 0.f);
        if (gr < n) v = ((const float4*)x)[(size_t)gr * 32 + c4];
        ((float4*)Xl)[rr * 33 + c4] = v;
    }
    __syncthreads();

    const int lane = t & 7;
    const int row  = t >> 3;
    const float* xrow = &Xl[row * XLD];
    float4 acc = make_float4(0.f, 0.f, 0.f, 0.f);
#pragma unroll
    for (int k = 0; k < DIN; ++k) {
        float xv = xrow[k];
        float4 w = Wl4[k * 8 + lane];
        acc.x += xv * w.x; acc.y += xv * w.y;
        acc.z += xv * w.z; acc.w += xv * w.w;
    }
    int r = rb + row;
    if (r < n) {
        float di = dinv[r];
        ushort4 sv;
        sv.x = f2bf(acc.x * di); sv.y = f2bf(acc.y * di);
        sv.z = f2bf(acc.z * di); sv.w = f2bf(acc.w * di);
        *(ushort4*)&mqc[(size_t)r * DH + 4 * lane] = sv;
    }
}

// one block per bucket.  FAST PATH: sentinel-padded node-sorted LDS layout
// (group of 16 lanes owns 8 nodes; per-group uniform u-loop, zero predication;
// lane loads a dword = 2 bf16 dims -> ~2x fewer instr/edge than round 12).
// FALLBACK (pad overflow / huge bucket): round-12 predicated chunked path.
__global__ void __launch_bounds__(256, 3)
agg1_kernel(const int* __restrict__ gbase, const int* __restrict__ gcnt,
            const int* __restrict__ degarr,
            unsigned int* __restrict__ binned,
            const unsigned short* __restrict__ mqc,
            const float* __restrict__ dinv,
            const float* __restrict__ b1, const float* __restrict__ W2,
            float2* __restrict__ m2q, int n) {
    __shared__ unsigned int sortedc[CHUNKB];   // 32 KB
    __shared__ int dg[NPB];
    __shared__ int coffs[NPB];   // compact offsets (for write-back / agg2)
    __shared__ int poffs[NPB];   // padded offsets
    __shared__ int cur[NPB];
    __shared__ int gmax[16];
    __shared__ int pbase[16];
    __shared__ int stmp[256];
    __shared__ int padtot;

    const int t = threadIdx.x;
    const int b = blockIdx.x;
    const int beg = gbase[b];
    const int cntb = gcnt[b];
    const int r0 = b << NPB_SHIFT;

    // degrees
    if (t < NPB) {
        int r = r0 + t;
        dg[t] = (r < n) ? degarr[r] : 0;
    }
    __syncthreads();

    // per-group max degree (group g owns nodes g*8..g*8+7)
    if (t < 16) {
        int mx = 0;
#pragma unroll
        for (int k = 0; k < 8; ++k) mx = max(mx, dg[t * 8 + k]);
        gmax[t] = mx;
    }
    int v = (t < NPB) ? dg[t] : 0;
    stmp[t] = v;
    __syncthreads();

    if (t == 0) {   // tiny serial scan of 16 group extents
        int run = 0;
#pragma unroll
        for (int g = 0; g < 16; ++g) { pbase[g] = run; run += 8 * gmax[g]; }
        padtot = run;
    }
    for (int o = 1; o < NPB; o <<= 1) {
        int xx = (t >= o) ? stmp[t - o] : 0;
        __syncthreads();
        stmp[t] += xx;
        __syncthreads();
    }
    if (t < NPB) coffs[t] = stmp[t] - v;
    __syncthreads();   // pbase/padtot/coffs all visible

    if (padtot <= CHUNKB && cntb <= CHUNKB) {
        // ================= fast path =================
        if (t < NPB) {
            int p = pbase[t >> 3] + (t & 7) * gmax[t >> 3];
            poffs[t] = p;
            cur[t] = p;
        }
        __syncthreads();

        // sentinel fill then scatter (one atomic-return per edge)
        for (int i = t; i < padtot; i += 256) sortedc[i] = (unsigned int)n;
        __syncthreads();
        for (int i = t; i < cntb; i += 256) {
            unsigned int en = binned[beg + i];
            int p = atomicAdd(&cur[en >> 17], 1);
            sortedc[p] = en & 0x1FFFFu;
        }
        __syncthreads();

        // gather: group g = t>>4 (16 lanes), lane l owns dims 2l,2l+1
        const int g = t >> 4, l = t & 15;
        const int mk = gmax[g];
        int bq[8];
#pragma unroll
        for (int q = 0; q < 8; ++q) bq[q] = poffs[g * 8 + q];

        float aLo[8], aHi[8];
#pragma unroll
        for (int q = 0; q < 8; ++q) { aLo[q] = 0.f; aHi[q] = 0.f; }

        for (int u = 0; u < mk; ++u) {
            unsigned int sv[8];
#pragma unroll
            for (int q = 0; q < 8; ++q) sv[q] = sortedc[bq[q] + u];
            unsigned int w[8];
#pragma unroll
            for (int q = 0; q < 8; ++q)
                w[q] = ((const unsigned int*)(mqc + (size_t)sv[q] * DH))[l];
#pragma unroll
            for (int q = 0; q < 8; ++q) {
                aLo[q] += bfLO(w[q]);
                aHi[q] += bfHI(w[q]);
            }
        }

        // compact write-back for agg2 (2 threads per node, sentinels skipped)
        {
            int j = t >> 1, hf = t & 1;
            int d = dg[j], cb = coffs[j], pb = poffs[j];
            for (int k = hf; k < d; k += 2)
                binned[beg + cb + k] = sortedc[pb + k];
        }

        // epilogue: self + ReLU + W2, reduce over 16 lanes (32 dims)
        float2 bb = ((const float2*)b1)[l];
        float4 w4 = ((const float4*)W2)[l];   // W2[2l][0..1], W2[2l+1][0..1]
#pragma unroll
        for (int q = 0; q < 8; ++q) {
            int r = r0 + g * 8 + q;
            if (r < n) {
                float di = dinv[r];
                unsigned int sw = ((const unsigned int*)(mqc + (size_t)r * DH))[l];
                float h0 = fmaxf(di * (aLo[q] + bfLO(sw)) + bb.x, 0.0f);
                float h1 = fmaxf(di * (aHi[q] + bfHI(sw)) + bb.y, 0.0f);
                float p0 = h0 * w4.x + h1 * w4.z;
                float p1 = h0 * w4.y + h1 * w4.w;
#pragma unroll
                for (int o = 8; o > 0; o >>= 1) {
                    p0 += __shfl_down(p0, o, 16);
                    p1 += __shfl_down(p1, o, 16);
                }
                if (l == 0) m2q[r] = make_float2(di * p0, di * p1);
            }
        }
        return;
    }

    // ================= fallback: round-12 predicated chunked path =========
    {
        const int lane = t & 31;
        const int half = t >> 5;
        float acc[16];
#pragma unroll
        for (int q = 0; q < 16; ++q) acc[q] = 0.0f;

        for (int off = 0; off < cntb; off += CHUNKB) {
            const int m = min(CHUNKB, cntb - off);

            if (t < NPB) cur[t] = 0;
            __syncthreads();
            for (int i = t; i < m; i += 256)
                atomicAdd(&cur[binned[beg + off + i] >> 17], 1);
            __syncthreads();

            int vv = (t < NPB) ? cur[t] : 0;
            stmp[t] = vv;
            __syncthreads();
            for (int o = 1; o < NPB; o <<= 1) {
                int xx = (t >= o) ? stmp[t - o] : 0;
                __syncthreads();
                stmp[t] += xx;
                __syncthreads();
            }
            if (t < NPB) { dg[t] = vv; poffs[t] = stmp[t] - vv; cur[t] = stmp[t] - vv; }
            __syncthreads();

            for (int i = t; i < m; i += 256) {
                unsigned int en = binned[beg + off + i];
                int p = atomicAdd(&cur[en >> 17], 1);
                sortedc[p] = en & 0x1FFFFu;
            }
            __syncthreads();

            int e0q[16], kq[16];
            int maxk = 0;
#pragma unroll
            for (int q = 0; q < 16; ++q) {
                int j = q * 8 + half;
                e0q[q] = poffs[j];
                kq[q] = dg[j];
                maxk = max(maxk, kq[q]);
            }
            for (int u = 0; u < maxk; ++u) {
                float val[16];
#pragma unroll
                for (int q = 0; q < 16; ++q) {
                    int idx = min(e0q[q] + u, m - 1);
                    int s = (int)sortedc[idx];
                    val[q] = bf2f(mqc[(size_t)s * DH + lane]);
                }
#pragma unroll
                for (int q = 0; q < 16; ++q)
                    acc[q] += (u < kq[q]) ? val[q] : 0.0f;
            }
            __syncthreads();
        }

#pragma unroll
        for (int q = 0; q < 16; ++q) {
            const int j = q * 8 + half;
            const int r = r0 + j;
            if (r < n) {
                float di = dinv[r];
                float a = acc[q] + bf2f(mqc[(size_t)r * DH + lane]);
                float h = fmaxf(di * a + b1[lane], 0.0f);
                float p0 = h * W2[lane * DOUT + 0];
                float p1 = h * W2[lane * DOUT + 1];
#pragma unroll
                for (int o = 16; o > 0; o >>= 1) {
                    p0 += __shfl_down(p0, o, 32);
                    p1 += __shfl_down(p1, o, 32);
                }
                if (lane == 0) m2q[r] = make_float2(di * p0, di * p1);
            }
        }
        // NOTE: fallback leaves binned unsorted; agg2's fallback handles it
        // only when cntb > CHUNKB, which is the same trigger except for the
        // (astronomically rare) pad-overflow-with-small-cntb case; cover it:
        if (cntb <= CHUNKB) {
            // re-sort compactly for agg2 using cur (ends) from last chunk
            // (single chunk since cntb <= CHUNKB)
            for (int i = t; i < cntb; i += 256) binned[beg + i] = sortedc[i];
        }
    }
}

// one block per bucket.  FAST PATH: binned is node-sorted -> atomic-free
// gather, 2 threads per node (split run), shuffle-combine.  FALLBACK: LDS
// fp32 atomics on unsorted entries.
__global__ void agg2_kernel(const int* __restrict__ gbase, const int* __restrict__ gcnt,
                            const int* __restrict__ degarr,
                            const unsigned int* __restrict__ binned,
                            const float2* __restrict__ m2q,
                            const float* __restrict__ dinv, const float* __restrict__ b2,
                            float* __restrict__ out, int n) {
    __shared__ int dg[NPB];
    __shared__ int offs[NPB];
    __shared__ int stmp[256];
    __shared__ float a0s[NPB], a1s[NPB];

    const int t = threadIdx.x;
    const int b = blockIdx.x;
    const int beg = gbase[b];
    const int cntb = gcnt[b];
    const int r0 = b << NPB_SHIFT;

    if (cntb <= CHUNKB) {
        if (t < NPB) {
            int r = r0 + t;
            dg[t] = (r < n) ? degarr[r] : 0;
        }
        __syncthreads();
        int v = (t < NPB) ? dg[t] : 0;
        stmp[t] = v;
        __syncthreads();
        for (int o = 1; o < NPB; o <<= 1) {
            int xx = (t >= o) ? stmp[t - o] : 0;
            __syncthreads();
            stmp[t] += xx;
            __syncthreads();
        }
        if (t < NPB) offs[t] = stmp[t] - v;
        __syncthreads();

        int j = t >> 1, hf = t & 1;
        int d = dg[j], o = offs[j];
        int lo = o + (hf ? (d >> 1) : 0);
        int hi = o + (hf ? d : (d >> 1));
        float a0 = 0.f, a1 = 0.f;
        for (int i = lo; i < hi; ++i) {
            int s = (int)(binned[beg + i] & 0x1FFFFu);
            float2 vv = m2q[s];
            a0 += vv.x; a1 += vv.y;
        }
        a0 += __shfl_down(a0, 1, 2);
        a1 += __shfl_down(a1, 1, 2);
        if (hf == 0) {
            int r = r0 + j;
            if (r < n) {
                float di = dinv[r];
                float2 self = m2q[r];
                out[(size_t)r * DOUT + 0] = di * (a0 + self.x) + b2[0];
                out[(size_t)r * DOUT + 1] = di * (a1 + self.y) + b2[1];
            }
        }
    } else {
        for (int i = t; i < NPB; i += 256) { a0s[i] = 0.f; a1s[i] = 0.f; }
        __syncthreads();
        for (int i = t; i < cntb; i += 256) {
            unsigned int entry = binned[beg + i];
            int sv = (int)(entry & 0x1FFFFu);
            int dl = (int)(entry >> 17);
            float2 vv = m2q[sv];
            atomicAdd(&a0s[dl], vv.x);
            atomicAdd(&a1s[dl], vv.y);
        }
        __syncthreads();
        for (int rl = t; rl < NPB; rl += 256) {
            int r = r0 + rl;
            if (r < n) {
                float di = dinv[r];
                float2 self = m2q[r];
                out[(size_t)r * DOUT + 0] = di * (a0s[rl] + self.x) + b2[0];
                out[(size_t)r * DOUT + 1] = di * (a1s[rl] + self.y) + b2[1];
            }
        }
    }
}

extern "C" void kernel_launch(void* const* d_in, const int* in_sizes, int n_in,
                              void* d_out, int out_size, void* d_ws, size_t ws_size,
                              hipStream_t stream) {
    const float* x  = (const float*)d_in[0];
    const int*   ei = (const int*)d_in[1];
    const float* W1 = (const float*)d_in[2];
    const float* b1 = (const float*)d_in[3];
    const float* W2 = (const float*)d_in[4];
    const float* b2 = (const float*)d_in[5];
    float* out = (float*)d_out;

    const int n = in_sizes[0] / DIN;
    const int e = in_sizes[1] / 2;
    const int* src = ei;
    const int* dst = ei + e;
    const int nbuk = (n + NPB - 1) >> NPB_SHIFT;   // 782 for n=100000

    char* ws = (char*)d_ws;
    float* dinv   = (float*)ws;          ws += (size_t)n * 4;
    int* degarr   = (int*)ws;            ws += (size_t)n * 4;
    int* gcnt     = (int*)ws;            ws += NBUK_MAX * 4;
    int* gbase    = (int*)ws;            ws += NBUK_MAX * 4;
    int* gcur     = (int*)ws;            ws += NBUK_MAX * 4;
    unsigned int* binned = (unsigned int*)ws;   ws += (size_t)e * 4;
    unsigned short* mqc  = (unsigned short*)ws; ws += ((size_t)n + 1) * DH * 2;
    float2* m2q   = (float2*)ws;

    const int B = 256;
    const int fill_blocks = (e + FILL_EDGES - 1) / FILL_EDGES;   // 391

    zero_gcnt_kernel<<<(nbuk + B - 1) / B, B, 0, stream>>>(gcnt, nbuk);
    bukhist_kernel<<<fill_blocks, B, 0, stream>>>(dst, gcnt, e, nbuk);
    scan_kernel<<<1, B, 0, stream>>>(gcnt, gbase, gcur, nbuk, mqc, n);
    binfill_kernel<<<fill_blocks, B, 0, stream>>>(src, dst, gcur, binned, e, nbuk);
    bdinv_kernel<<<nbuk, B, 0, stream>>>(gbase, gcnt, binned, dinv, degarr, n);
    gemm1_kernel<<<(n + 31) / 32, B, 0, stream>>>(x, W1, dinv, mqc, n);
    agg1_kernel<<<nbuk, B, 0, stream>>>(gbase, gcnt, degarr, binned, mqc, dinv, b1, W2, m2q, n);
    agg2_kernel<<<nbuk, B, 0, stream>>>(gbase, gcnt, degarr, binned, m2q, dinv, b2, out, n);
}